// Round 12
// baseline (237.355 us; speedup 1.0000x reference)
//
#include <hip/hip_runtime.h>
#include <math.h>

#define Tt 1024
#define Dd 1024
#define Hh 16
#define DHh 64
#define MAXPOS 64
#define BTt 2048

typedef short short8 __attribute__((ext_vector_type(8)));
typedef float floatx4 __attribute__((ext_vector_type(4)));

#define MFMA16 __builtin_amdgcn_mfma_f32_16x16x32_bf16

__device__ __forceinline__ unsigned short f2bf(float f) {
    unsigned u;
    __builtin_memcpy(&u, &f, 4);
    u = (u + 0x7FFFu + ((u >> 16) & 1u)) >> 16;
    return (unsigned short)u;
}
__device__ __forceinline__ float bf2fs(short s) {
    unsigned u = ((unsigned)(unsigned short)s) << 16;
    float f;
    __builtin_memcpy(&f, &u, 4);
    return f;
}
__device__ __forceinline__ float frcp(float x) { return __builtin_amdgcn_rcpf(x); }
// async global->LDS 16B/lane: LDS dest = wave-uniform base + lane*16
__device__ __forceinline__ void async_ld16(const short* g, short* l) {
    __builtin_amdgcn_global_load_lds(
        (const __attribute__((address_space(1))) unsigned int*)g,
        (__attribute__((address_space(3))) unsigned int*)l, 16, 0, 0);
}

// ---------------- fp32 -> bf16 pre-conversion (x + 4 weights) -------------------
__global__ __launch_bounds__(256) void conv_bf16(
    const float* __restrict__ x,  const float* __restrict__ W0,
    const float* __restrict__ W1, const float* __restrict__ W2,
    const float* __restrict__ W3,
    short* __restrict__ xb, short* __restrict__ w0b, short* __restrict__ w1b,
    short* __restrict__ w2b, short* __restrict__ w3b)
{
    const float* src; short* dst; int n;
    switch (blockIdx.y) {
        case 0:  src = x;  dst = xb;  n = BTt * Dd; break;
        case 1:  src = W0; dst = w0b; n = Dd * Dd;  break;
        case 2:  src = W1; dst = w1b; n = Dd * Dd;  break;
        case 3:  src = W2; dst = w2b; n = Dd * Dd;  break;
        default: src = W3; dst = w3b; n = Dd * Dd;  break;
    }
    int idx = (blockIdx.x * 256 + threadIdx.x) * 8;
    if (idx >= n) return;
    floatx4 a0 = *(const floatx4*)&src[idx];
    floatx4 a1 = *(const floatx4*)&src[idx + 4];
    short8 s;
    for (int e = 0; e < 4; ++e) {
        s[e]     = (short)f2bf(a0[e]);
        s[e + 4] = (short)f2bf(a1[e]);
    }
    *(short8*)&dst[idx] = s;
}

// ------------- MFMA GEMM: C = A[M,K] * W[N,K]^T + bias (bf16 in, bf16 MFMA)
// m97-style staging: global_load_lds_dwordx4, each inst covers 8 consecutive
// rows x 128B contiguous segments (8 lanes/row) into UNPADDED [128][64] LDS.
#define BM 128
#define BN 128
#define BKK 64

template <int MODE>   // 0: fp32 out, 1: bf16 out
__device__ __forceinline__ void gemm_body(const short* __restrict__ A,
                                          const short* __restrict__ W,
                                          const float* __restrict__ bias,
                                          void* __restrict__ Cout,
                                          int N, int K)
{
    __shared__ __align__(16) short Ash[BM * BKK];   // 16 KB unpadded [128][64]
    __shared__ __align__(16) short Bsh[BN * BKK];   // 16 KB
    const int t = threadIdx.x;
    const int lane = t & 63, wave = t >> 6;
    const int wm = wave >> 1, wn = wave & 1;
    const int quad = lane >> 4, l16 = lane & 15;
    const int lr8 = lane >> 3, lc8 = lane & 7;      // 8 rows/inst, 8 lanes/row
    const int row0 = blockIdx.x * BM, col0 = blockIdx.y * BN;

    floatx4 acc[4][4];
    for (int a = 0; a < 4; ++a)
        for (int b2 = 0; b2 < 4; ++b2)
            acc[a][b2] = (floatx4){0.f, 0.f, 0.f, 0.f};

    for (int kb = 0; kb < K; kb += BKK) {
        __syncthreads();
        for (int i2 = 0; i2 < 4; ++i2) {
            int ii = wave * 4 + i2;                 // 0..15, rows 8*ii..8*ii+7
            async_ld16(&A[(size_t)(row0 + ii * 8 + lr8) * K + kb + lc8 * 8],
                       &Ash[ii * 512]);
            async_ld16(&W[(size_t)(col0 + ii * 8 + lr8) * K + kb + lc8 * 8],
                       &Bsh[ii * 512]);
        }
        __syncthreads();   // compiler emits s_waitcnt vmcnt(0) before barrier
        for (int ks = 0; ks < BKK / 32; ++ks) {
            short8 af[4], bfr[4];
            for (int tm = 0; tm < 4; ++tm)
                af[tm] = *(short8*)&Ash[(wm * 64 + tm * 16 + l16) * 64 + ks * 32 + quad * 8];
            for (int tn = 0; tn < 4; ++tn)
                bfr[tn] = *(short8*)&Bsh[(wn * 64 + tn * 16 + l16) * 64 + ks * 32 + quad * 8];
            for (int tm = 0; tm < 4; ++tm)
                for (int tn = 0; tn < 4; ++tn)
                    acc[tm][tn] = MFMA16(af[tm], bfr[tn], acc[tm][tn], 0, 0, 0);
        }
    }
    for (int tm = 0; tm < 4; ++tm)
        for (int tn = 0; tn < 4; ++tn) {
            int col = col0 + wn * 64 + tn * 16 + l16;
            float bv = bias[col];
            for (int r = 0; r < 4; ++r) {
                int row = row0 + wm * 64 + tm * 16 + quad * 4 + r;
                float v = acc[tm][tn][r] + bv;
                if (MODE == 0) ((float*)Cout)[(size_t)row * N + col] = v;
                else           ((short*)Cout)[(size_t)row * N + col] = (short)f2bf(v);
            }
        }
}

__global__ __launch_bounds__(256) void gemm_qkv(
    const short* __restrict__ xb,
    const short* __restrict__ Wqb, const short* __restrict__ Wkb,
    const short* __restrict__ Wvb,
    const float* __restrict__ bq, const float* __restrict__ bk,
    const float* __restrict__ bv,
    short* __restrict__ Qb, short* __restrict__ Kb, short* __restrict__ Vrow)
{
    if (blockIdx.z == 0)      gemm_body<1>(xb, Wqb, bq, Qb, Dd, Dd);
    else if (blockIdx.z == 1) gemm_body<1>(xb, Wkb, bk, Kb, Dd, Dd);
    else                      gemm_body<1>(xb, Wvb, bv, Vrow, Dd, Dd);
}

__global__ __launch_bounds__(256) void gemm_o(
    const short* __restrict__ A, const short* __restrict__ W,
    const float* __restrict__ bias, float* __restrict__ C)
{
    gemm_body<0>(A, W, bias, C, Dd, Dd);
}

// ------- merged kernel: blockIdx.x < 256 -> gate sums; >= 256 -> V transpose ----
__global__ __launch_bounds__(256) void vt_gates(
    const short* __restrict__ Q, const short* __restrict__ K,
    const short* __restrict__ Vrow, short* __restrict__ Vt,
    float* __restrict__ gts)
{
    __shared__ __align__(16) short Qt[32 * 72];
    __shared__ __align__(16) short KV[128 * 72];   // vt branch reuses as 64x72 tile
    __shared__ float Sld[32 * 132];
    __shared__ float redg[32 * 8];

    const int t = threadIdx.x;

    if (blockIdx.x >= 256) {
        // ---- V transpose: Vt[b][d][j] = Vrow[b][j][d], 64x64 tiles ----
        const int j0 = (blockIdx.x - 256) * 64, d0 = blockIdx.y * 64, b = blockIdx.z;
        short* L = KV;
        for (int s = 0; s < 2; ++s) {
            int c = t * 2 + s;
            int jr = c >> 3, c8 = c & 7;
            *(short8*)&L[jr * 72 + c8 * 8] =
                *(const short8*)&Vrow[((size_t)(b * Tt + j0 + jr)) * Dd + d0 + c8 * 8];
        }
        __syncthreads();
        for (int s = 0; s < 2; ++s) {
            int c = t * 2 + s;
            int dr = c >> 3, c8 = c & 7;
            short8 v;
            for (int e = 0; e < 8; ++e) v[e] = L[(c8 * 8 + e) * 72 + dr];
            *(short8*)&Vt[((size_t)(b * Dd + d0 + dr)) * Tt + j0 + c8 * 8] = v;
        }
        return;
    }

    // ---- gate sums: per-(row, j-tile) sigmoid sums ----
    const int it = blockIdx.x >> 3, jt = blockIdx.x & 7;
    const int h = blockIdx.y, b = blockIdx.z;
    const int i0 = it * 32, j0 = jt * 128;
    const int lane = t & 63, wave = t >> 6;
    const int quad = lane >> 4, l16 = lane & 15;

    float* g = &gts[(((size_t)(b * Hh + h)) * Tt + i0) * 8 + jt];
    if (j0 > i0 + 31) {                     // tile fully masked
        if (t < 32) g[t * 8] = 0.f;
        return;
    }

    const float inv_scale = 0.125f;

    {
        int r = t >> 3, c = t & 7;
        *(short8*)&Qt[r * 72 + c * 8] =
            *(const short8*)&Q[((size_t)(b * Tt + i0 + r)) * Dd + h * DHh + c * 8];
    }
    for (int e = 0; e < 4; ++e) {
        int ch = t + 256 * e;
        int jr = ch >> 3, c = ch & 7;
        *(short8*)&KV[jr * 72 + c * 8] =
            *(const short8*)&K[((size_t)(b * Tt + j0 + jr)) * Dd + h * DHh + c * 8];
    }
    __syncthreads();
    {
        int ntA = 2 * wave, ntB = ntA + 1;
        floatx4 c00 = {0,0,0,0}, c01 = {0,0,0,0}, c10 = {0,0,0,0}, c11 = {0,0,0,0};
        for (int ks = 0; ks < 2; ++ks) {
            short8 a0 = *(short8*)&Qt[(l16) * 72 + ks * 32 + quad * 8];
            short8 a1 = *(short8*)&Qt[(16 + l16) * 72 + ks * 32 + quad * 8];
            short8 b0 = *(short8*)&KV[(ntA * 16 + l16) * 72 + ks * 32 + quad * 8];
            short8 b1 = *(short8*)&KV[(ntB * 16 + l16) * 72 + ks * 32 + quad * 8];
            c00 = MFMA16(a0, b0, c00, 0, 0, 0);
            c01 = MFMA16(a0, b1, c01, 0, 0, 0);
            c10 = MFMA16(a1, b0, c10, 0, 0, 0);
            c11 = MFMA16(a1, b1, c11, 0, 0, 0);
        }
        for (int r = 0; r < 4; ++r) {
            Sld[(quad * 4 + r) * 132 + ntA * 16 + l16] = c00[r];
            Sld[(quad * 4 + r) * 132 + ntB * 16 + l16] = c01[r];
            Sld[(16 + quad * 4 + r) * 132 + ntA * 16 + l16] = c10[r];
            Sld[(16 + quad * 4 + r) * 132 + ntB * 16 + l16] = c11[r];
        }
    }
    __syncthreads();
    {
        const int sr = t >> 3, ss = t & 7, irow = i0 + sr;
        float gs = 0.f;
        for (int e = 0; e < 16; ++e) {
            int jl = ss * 16 + e, j = j0 + jl;
            if (j <= irow) {
                // g = 1 - 1/(1+e^{x}) — SAME formula as attn kernel (consistency)
                float ex = __expf(Sld[sr * 132 + jl] * inv_scale);
                gs += 1.f - frcp(1.f + ex);
            }
        }
        redg[sr * 8 + ss] = gs;
    }
    __syncthreads();
    if (t < 32) {
        float s2 = 0.f;
        for (int s = 0; s < 8; ++s) s2 += redg[t * 8 + s];
        g[t * 8] = s2;
    }
}

// ---------------- fused attn: scores + no-max softmax + PV (single pass) --------
// Per-element: ex=exp(qk/8) [1 trans]; g=1-rcp(1+ex) [1 trans]; p=ex*lerp(qpeE).
// qpeE = exp(qpe/8) fp32 table (lerp-of-exp vs exp-of-lerp err <= 2e-4).
__global__ __launch_bounds__(256) void cope_attn(
    const short* __restrict__ Q, const short* __restrict__ K,
    const short* __restrict__ Vt, const float* __restrict__ PE,
    const float* __restrict__ gts, short* __restrict__ AOb)
{
    const int it = (int)gridDim.x - 1 - (int)blockIdx.x;   // heavy tiles first
    const int h = blockIdx.y, b = blockIdx.z;
    const int i0 = it * 32;
    const int t = threadIdx.x, lane = t & 63, wave = t >> 6;
    const int quad = lane >> 4, l16 = lane & 15;

    __shared__ __align__(16) float Sld[32 * 132];   // setup: aliased as Q tile
    __shared__ __align__(16) short KV[128 * 72];    // PE / K[128][72] / V[64][136]
    __shared__ __align__(16) short Pb[32 * 136];
    __shared__ float qpeE[32 * 66];                 // exp(qpe/8), fp32
    __shared__ float lrow[32];

    const float inv_scale = 0.125f;
    const int sr = t >> 3, ss = t & 7, irow = i0 + sr;

    float grow[8];
    {
        const float* gp = &gts[(((size_t)(b * Hh + h)) * Tt + i0 + sr) * 8];
        for (int k = 0; k < 8; ++k) grow[k] = gp[k];
    }
    float tot = 0.f;
    for (int k = 0; k < 8; ++k) tot += grow[k];

    short* QtS = (short*)Sld;
    {
        int r = t >> 3, c = t & 7;
        *(short8*)&QtS[r * 72 + c * 8] =
            *(const short8*)&Q[((size_t)(b * Tt + i0 + r)) * Dd + h * DHh + c * 8];
    }
    for (int e = 0; e < 16; ++e) {
        int idx = t + 256 * e;
        int p = idx >> 6, d = idx & 63;
        KV[p * 72 + d] = (short)f2bf(PE[((size_t)h * MAXPOS + p) * DHh + d]);
    }
    __syncthreads();

    short8 qa[2][2];
    for (int rb = 0; rb < 2; ++rb)
        for (int ks = 0; ks < 2; ++ks)
            qa[rb][ks] = *(short8*)&QtS[(rb * 16 + l16) * 72 + ks * 32 + quad * 8];

    // qpe table via MFMA (M=32, N=64, K=64) -> exp(qpe/8) fp32
    {
        int mt = wave >> 1;
        int ntA = 2 * (wave & 1), ntB = ntA + 1;
        floatx4 c0f = {0, 0, 0, 0}, c1f = {0, 0, 0, 0};
        for (int ks = 0; ks < 2; ++ks) {
            short8 b0 = *(short8*)&KV[(ntA * 16 + l16) * 72 + ks * 32 + quad * 8];
            short8 b1 = *(short8*)&KV[(ntB * 16 + l16) * 72 + ks * 32 + quad * 8];
            c0f = MFMA16(qa[mt][ks], b0, c0f, 0, 0, 0);
            c1f = MFMA16(qa[mt][ks], b1, c1f, 0, 0, 0);
        }
        for (int r = 0; r < 4; ++r) {
            qpeE[(mt * 16 + quad * 4 + r) * 66 + ntA * 16 + l16] = __expf(c0f[r] * inv_scale);
            qpeE[(mt * 16 + quad * 4 + r) * 66 + ntB * 16 + l16] = __expf(c1f[r] * inv_scale);
        }
    }

    const int JT = (i0 + 159) >> 7;
    floatx4 o0 = {0, 0, 0, 0}, o1 = {0, 0, 0, 0};
    const int pv_mt = wave >> 1;
    const int pv_ntA = 2 * (wave & 1), pv_ntB = pv_ntA + 1;
    float l_acc = 0.f;
    float baseAcc = 0.f;

    short8 kreg[4];
    for (int e = 0; e < 4; ++e) {
        int ch = t + 256 * e;
        int jr = ch >> 3, c = ch & 7;
        kreg[e] = *(const short8*)&K[((size_t)(b * Tt + jr)) * Dd + h * DHh + c * 8];
    }

    for (int jt = 0; jt < JT; ++jt) {
        const int j0 = jt * 128;
        __syncthreads();                                    // A: KV free
        for (int e = 0; e < 4; ++e) {
            int ch = t + 256 * e;
            int jr = ch >> 3, c = ch & 7;
            *(short8*)&KV[jr * 72 + c * 8] = kreg[e];
        }
        __syncthreads();                                    // B: K staged
        {
            int ntA = 2 * wave, ntB = ntA + 1;
            floatx4 c00 = {0,0,0,0}, c01 = {0,0,0,0}, c10 = {0,0,0,0}, c11 = {0,0,0,0};
            for (int ks = 0; ks < 2; ++ks) {
                short8 b0 = *(short8*)&KV[(ntA * 16 + l16) * 72 + ks * 32 + quad * 8];
                short8 b1 = *(short8*)&KV[(ntB * 16 + l16) * 72 + ks * 32 + quad * 8];
                c00 = MFMA16(qa[0][ks], b0, c00, 0, 0, 0);
                c01 = MFMA16(qa[0][ks], b1, c01, 0, 0, 0);
                c10 = MFMA16(qa[1][ks], b0, c10, 0, 0, 0);
                c11 = MFMA16(qa[1][ks], b1, c11, 0, 0, 0);
            }
            for (int r = 0; r < 4; ++r) {
                Sld[(quad * 4 + r) * 132 + ntA * 16 + l16] = c00[r];
                Sld[(quad * 4 + r) * 132 + ntB * 16 + l16] = c01[r];
                Sld[(16 + quad * 4 + r) * 132 + ntA * 16 + l16] = c10[r];
                Sld[(16 + quad * 4 + r) * 132 + ntB * 16 + l16] = c11[r];
            }
        }
        __syncthreads();                                    // C: S ready
        short8 vreg[4];
        for (int e = 0; e < 4; ++e) {
            int ch = t + 256 * e;
            int d = ch >> 4, c = ch & 15;
            vreg[e] = *(const short8*)&Vt[((size_t)(b * Dd + h * DHh + d)) * Tt + j0 + c * 8];
        }
        if (jt + 1 < JT) {
            for (int e = 0; e < 4; ++e) {
                int ch = t + 256 * e;
                int jr = ch >> 3, c = ch & 7;
                kreg[e] = *(const short8*)&K[((size_t)(b * Tt + j0 + 128 + jr)) * Dd + h * DHh + c * 8];
            }
        }
        {
            floatx4 qv[4];
            for (int q4 = 0; q4 < 4; ++q4)
                qv[q4] = *(floatx4*)&Sld[sr * 132 + ss * 16 + q4 * 4];
            float exv[16], gt[16];
            float gs = 0.f;
            for (int e = 0; e < 16; ++e) {
                int j = j0 + ss * 16 + e;
                float ex = __expf(qv[e >> 2][e & 3] * inv_scale);
                float g = (j <= irow) ? 1.f - frcp(1.f + ex) : 0.f;
                exv[e] = ex;
                gt[e] = g;
                gs += g;
            }
            float inc = gs;
            for (int d2 = 1; d2 < 8; d2 <<= 1) {
                float n = __shfl_up(inc, d2, 64);
                if ((lane & 7) >= d2) inc += n;
            }
            float base = baseAcc + (inc - gs);
            float run = 0.f;
            short8 p0, p1;
            for (int e = 0; e < 16; ++e) {
                run += gt[e];
                int j = j0 + ss * 16 + e;
                float pos = tot - (base + run);
                pos = fminf(fmaxf(pos, 0.f), 63.f);
                float pf = floorf(pos);
                float al = pos - pf;
                int fi = (int)pf;
                int ci = fi + (al > 0.f ? 1 : 0);
                if (ci > 63) ci = 63;
                float qe = (1.f - al) * qpeE[sr * 66 + fi] + al * qpeE[sr * 66 + ci];
                float p = (j <= irow) ? exv[e] * qe : 0.f;
                if (e < 8) p0[e] = (short)f2bf(p); else p1[e - 8] = (short)f2bf(p);
                l_acc += p;
            }
            *(short8*)&Pb[sr * 136 + ss * 16]     = p0;
            *(short8*)&Pb[sr * 136 + ss * 16 + 8] = p1;
            baseAcc += grow[jt];
        }
        for (int e = 0; e < 4; ++e) {
            int ch = t + 256 * e;
            int d = ch >> 4, c = ch & 15;
            *(short8*)&KV[d * 136 + c * 8] = vreg[e];
        }
        __syncthreads();                                    // D: Pb + V ready
        for (int ks = 0; ks < 4; ++ks) {
            short8 a  = *(short8*)&Pb[(pv_mt * 16 + l16) * 136 + ks * 32 + quad * 8];
            short8 b0 = *(short8*)&KV[(pv_ntA * 16 + l16) * 136 + ks * 32 + quad * 8];
            short8 b1 = *(short8*)&KV[(pv_ntB * 16 + l16) * 136 + ks * 32 + quad * 8];
            o0 = MFMA16(a, b0, o0, 0, 0, 0);
            o1 = MFMA16(a, b1, o1, 0, 0, 0);
        }
    }
    float lr = l_acc;
    for (int d2 = 4; d2 >= 1; d2 >>= 1) lr += __shfl_xor(lr, d2, 64);
    if (ss == 0) lrow[sr] = lr;
    __syncthreads();
    for (int r = 0; r < 4; ++r) {
        int row = pv_mt * 16 + quad * 4 + r;
        float inv = frcp(lrow[row]);
        size_t off = ((size_t)(b * Tt + i0 + row)) * Dd + h * DHh;
        AOb[off + pv_ntA * 16 + l16] = (short)f2bf(o0[r] * inv);
        AOb[off + pv_ntB * 16 + l16] = (short)f2bf(o1[r] * inv);
    }
}

// ---------------- launch ---------------------------------------------------------
extern "C" void kernel_launch(void* const* d_in, const int* in_sizes, int n_in,
                              void* d_out, int out_size, void* d_ws, size_t ws_size,
                              hipStream_t stream)
{
    const float* x  = (const float*)d_in[0];
    const float* Wq = (const float*)d_in[1];
    const float* bq = (const float*)d_in[2];
    const float* Wk = (const float*)d_in[3];
    const float* bk = (const float*)d_in[4];
    const float* Wv = (const float*)d_in[5];
    const float* bv = (const float*)d_in[6];
    const float* Wo = (const float*)d_in[7];
    const float* bo = (const float*)d_in[8];
    const float* pe = (const float*)d_in[9];
    // d_in[10]: causal mask (j > i) — structural, unused

    short* xb   = (short*)d_ws;                         //  4 MB
    short* Wqb  = xb   + (size_t)BTt * Dd;              //  2 MB
    short* Wkb  = Wqb  + (size_t)Dd * Dd;               //  2 MB
    short* Wvb  = Wkb  + (size_t)Dd * Dd;               //  2 MB
    short* Wob  = Wvb  + (size_t)Dd * Dd;               //  2 MB
    short* Qb   = Wob  + (size_t)Dd * Dd;               //  4 MB
    short* Kb   = Qb   + (size_t)BTt * Dd;              //  4 MB
    short* Vrow = Kb   + (size_t)BTt * Dd;              //  4 MB
    short* Vtg  = Vrow + (size_t)BTt * Dd;              //  4 MB
    short* AOb  = Vtg  + (size_t)BTt * Dd;              //  4 MB
    float* gts  = (float*)(AOb + (size_t)BTt * Dd);     //  1 MB

    dim3 gc(BTt * Dd / 8 / 256, 5);
    conv_bf16<<<gc, 256, 0, stream>>>(x, Wq, Wk, Wv, Wo, xb, Wqb, Wkb, Wvb, Wob);

    dim3 gq(BTt / BM, Dd / BN, 3);
    gemm_qkv<<<gq, 256, 0, stream>>>(xb, Wqb, Wkb, Wvb, bq, bk, bv, Qb, Kb, Vrow);

    dim3 gg(272, Hh, 2);    // x<256: gate sums; x>=256: V transpose (y = d-tile)
    vt_gates<<<gg, 256, 0, stream>>>(Qb, Kb, Vrow, Vtg, gts);

    dim3 ga(Tt / 32, Hh, 2);
    cope_attn<<<ga, 256, 0, stream>>>(Qb, Kb, Vtg, pe, gts, AOb);

    dim3 go(BTt / BM, Dd / BN, 1);
    gemm_o<<<go, 256, 0, stream>>>(AOb, Wob, bo, (float*)d_out);
}

// Round 13
// 217.028 us; speedup vs baseline: 1.0937x; 1.0937x over previous
//
#include <hip/hip_runtime.h>
#include <math.h>

#define Tt 1024
#define Dd 1024
#define Hh 16
#define DHh 64
#define MAXPOS 64
#define BTt 2048

typedef short short8 __attribute__((ext_vector_type(8)));
typedef float floatx4 __attribute__((ext_vector_type(4)));

#define MFMA16 __builtin_amdgcn_mfma_f32_16x16x32_bf16

__device__ __forceinline__ unsigned short f2bf(float f) {
    unsigned u;
    __builtin_memcpy(&u, &f, 4);
    u = (u + 0x7FFFu + ((u >> 16) & 1u)) >> 16;
    return (unsigned short)u;
}
__device__ __forceinline__ float bf2fs(short s) {
    unsigned u = ((unsigned)(unsigned short)s) << 16;
    float f;
    __builtin_memcpy(&f, &u, 4);
    return f;
}
// fast sigmoid: v_rcp_f32 instead of IEEE div (~1 ulp; threshold margin is 4x)
__device__ __forceinline__ float fsigm(float x) {
    return __builtin_amdgcn_rcpf(1.f + __expf(-x));
}

// ---------------- fp32 -> bf16 pre-conversion (x + 4 weights) -------------------
__global__ __launch_bounds__(256) void conv_bf16(
    const float* __restrict__ x,  const float* __restrict__ W0,
    const float* __restrict__ W1, const float* __restrict__ W2,
    const float* __restrict__ W3,
    short* __restrict__ xb, short* __restrict__ w0b, short* __restrict__ w1b,
    short* __restrict__ w2b, short* __restrict__ w3b)
{
    const float* src; short* dst; int n;
    switch (blockIdx.y) {
        case 0:  src = x;  dst = xb;  n = BTt * Dd; break;
        case 1:  src = W0; dst = w0b; n = Dd * Dd;  break;
        case 2:  src = W1; dst = w1b; n = Dd * Dd;  break;
        case 3:  src = W2; dst = w2b; n = Dd * Dd;  break;
        default: src = W3; dst = w3b; n = Dd * Dd;  break;
    }
    int idx = (blockIdx.x * 256 + threadIdx.x) * 8;
    if (idx >= n) return;
    floatx4 a0 = *(const floatx4*)&src[idx];
    floatx4 a1 = *(const floatx4*)&src[idx + 4];
    short8 s;
    for (int e = 0; e < 4; ++e) {
        s[e]     = (short)f2bf(a0[e]);
        s[e + 4] = (short)f2bf(a1[e]);
    }
    *(short8*)&dst[idx] = s;
}

// ------------- MFMA GEMM: C = A[M,K] * W[N,K]^T + bias (bf16 in, bf16 MFMA)
// R11-proven staging: padded LDS (stride 72), coalesced short8 loads via VGPR.
#define BM 128
#define BN 128
#define BKK 64
#define LDSS 72

template <int MODE>   // 0: fp32 out, 1: bf16 out
__device__ __forceinline__ void gemm_body(const short* __restrict__ A,
                                          const short* __restrict__ W,
                                          const float* __restrict__ bias,
                                          void* __restrict__ Cout,
                                          int N, int K)
{
    __shared__ __align__(16) short Ash[BM * LDSS];
    __shared__ __align__(16) short Bsh[BN * LDSS];
    const int t = threadIdx.x;
    const int lane = t & 63, wave = t >> 6;
    const int wm = wave >> 1, wn = wave & 1;
    const int quad = lane >> 4, l16 = lane & 15;
    const int row0 = blockIdx.x * BM, col0 = blockIdx.y * BN;

    floatx4 acc[4][4];
    for (int a = 0; a < 4; ++a)
        for (int b2 = 0; b2 < 4; ++b2)
            acc[a][b2] = (floatx4){0.f, 0.f, 0.f, 0.f};

    for (int kb = 0; kb < K; kb += BKK) {
        __syncthreads();
        for (int q2 = 0; q2 < 4; ++q2) {
            int ch = t + 256 * q2;
            int r = ch >> 3, c = ch & 7;
            *(short8*)&Ash[r * LDSS + c * 8] =
                *(const short8*)&A[(size_t)(row0 + r) * K + kb + c * 8];
            *(short8*)&Bsh[r * LDSS + c * 8] =
                *(const short8*)&W[(size_t)(col0 + r) * K + kb + c * 8];
        }
        __syncthreads();
        for (int ks = 0; ks < BKK / 32; ++ks) {
            short8 af[4], bfr[4];
            for (int tm = 0; tm < 4; ++tm)
                af[tm] = *(short8*)&Ash[(wm * 64 + tm * 16 + l16) * LDSS + ks * 32 + quad * 8];
            for (int tn = 0; tn < 4; ++tn)
                bfr[tn] = *(short8*)&Bsh[(wn * 64 + tn * 16 + l16) * LDSS + ks * 32 + quad * 8];
            for (int tm = 0; tm < 4; ++tm)
                for (int tn = 0; tn < 4; ++tn)
                    acc[tm][tn] = MFMA16(af[tm], bfr[tn], acc[tm][tn], 0, 0, 0);
        }
    }
    for (int tm = 0; tm < 4; ++tm)
        for (int tn = 0; tn < 4; ++tn) {
            int col = col0 + wn * 64 + tn * 16 + l16;
            float bv = bias[col];
            for (int r = 0; r < 4; ++r) {
                int row = row0 + wm * 64 + tm * 16 + quad * 4 + r;
                float v = acc[tm][tn][r] + bv;
                if (MODE == 0) ((float*)Cout)[(size_t)row * N + col] = v;
                else           ((short*)Cout)[(size_t)row * N + col] = (short)f2bf(v);
            }
        }
}

__global__ __launch_bounds__(256) void gemm_qkv(
    const short* __restrict__ xb,
    const short* __restrict__ Wqb, const short* __restrict__ Wkb,
    const short* __restrict__ Wvb,
    const float* __restrict__ bq, const float* __restrict__ bk,
    const float* __restrict__ bv,
    short* __restrict__ Qb, short* __restrict__ Kb, short* __restrict__ Vrow)
{
    if (blockIdx.z == 0)      gemm_body<1>(xb, Wqb, bq, Qb, Dd, Dd);
    else if (blockIdx.z == 1) gemm_body<1>(xb, Wkb, bk, Kb, Dd, Dd);
    else                      gemm_body<1>(xb, Wvb, bv, Vrow, Dd, Dd);
}

__global__ __launch_bounds__(256) void gemm_o(
    const short* __restrict__ A, const short* __restrict__ W,
    const float* __restrict__ bias, float* __restrict__ C)
{
    gemm_body<0>(A, W, bias, C, Dd, Dd);
}

// ------- merged kernel: blockIdx.x < 256 -> gate sums; >= 256 -> V transpose ----
// Gates: sigmoid-sums reduced DIRECTLY from MFMA C-layout registers via
// shfl_xor butterflies (no S round-trip through LDS). LDS ~23.6 KB.
__global__ __launch_bounds__(256) void vt_gates(
    const short* __restrict__ Q, const short* __restrict__ K,
    const short* __restrict__ Vrow, short* __restrict__ Vt,
    float* __restrict__ gts)
{
    __shared__ __align__(16) short Qt[32 * 72];
    __shared__ __align__(16) short KV[128 * 72];   // vt branch reuses as 64x72 tile
    __shared__ float redg[32 * 4];

    const int t = threadIdx.x;

    if (blockIdx.x >= 256) {
        // ---- V transpose: Vt[b][d][j] = Vrow[b][j][d], 64x64 tiles ----
        const int j0 = (blockIdx.x - 256) * 64, d0 = blockIdx.y * 64, b = blockIdx.z;
        short* L = KV;
        for (int s = 0; s < 2; ++s) {
            int c = t * 2 + s;
            int jr = c >> 3, c8 = c & 7;
            *(short8*)&L[jr * 72 + c8 * 8] =
                *(const short8*)&Vrow[((size_t)(b * Tt + j0 + jr)) * Dd + d0 + c8 * 8];
        }
        __syncthreads();
        for (int s = 0; s < 2; ++s) {
            int c = t * 2 + s;
            int dr = c >> 3, c8 = c & 7;
            short8 v;
            for (int e = 0; e < 8; ++e) v[e] = L[(c8 * 8 + e) * 72 + dr];
            *(short8*)&Vt[((size_t)(b * Dd + d0 + dr)) * Tt + j0 + c8 * 8] = v;
        }
        return;
    }

    // ---- gate sums: per-(row, j-tile) sigmoid sums, register-reduced ----
    const int it = blockIdx.x >> 3, jt = blockIdx.x & 7;
    const int h = blockIdx.y, b = blockIdx.z;
    const int i0 = it * 32, j0 = jt * 128;
    const int lane = t & 63, wave = t >> 6;
    const int quad = lane >> 4, l16 = lane & 15;

    float* g = &gts[(((size_t)(b * Hh + h)) * Tt + i0) * 8 + jt];
    if (j0 > i0 + 31) {                     // tile fully masked
        if (t < 32) g[t * 8] = 0.f;
        return;
    }

    const float inv_scale = 0.125f;

    {
        int r = t >> 3, c = t & 7;
        *(short8*)&Qt[r * 72 + c * 8] =
            *(const short8*)&Q[((size_t)(b * Tt + i0 + r)) * Dd + h * DHh + c * 8];
    }
    for (int e = 0; e < 4; ++e) {
        int ch = t + 256 * e;
        int jr = ch >> 3, c = ch & 7;
        *(short8*)&KV[jr * 72 + c * 8] =
            *(const short8*)&K[((size_t)(b * Tt + j0 + jr)) * Dd + h * DHh + c * 8];
    }
    __syncthreads();

    int ntA = 2 * wave, ntB = ntA + 1;
    floatx4 c00 = {0,0,0,0}, c01 = {0,0,0,0}, c10 = {0,0,0,0}, c11 = {0,0,0,0};
    for (int ks = 0; ks < 2; ++ks) {
        short8 a0 = *(short8*)&Qt[(l16) * 72 + ks * 32 + quad * 8];
        short8 a1 = *(short8*)&Qt[(16 + l16) * 72 + ks * 32 + quad * 8];
        short8 b0 = *(short8*)&KV[(ntA * 16 + l16) * 72 + ks * 32 + quad * 8];
        short8 b1 = *(short8*)&KV[(ntB * 16 + l16) * 72 + ks * 32 + quad * 8];
        c00 = MFMA16(a0, b0, c00, 0, 0, 0);
        c01 = MFMA16(a0, b1, c01, 0, 0, 0);
        c10 = MFMA16(a1, b0, c10, 0, 0, 0);
        c11 = MFMA16(a1, b1, c11, 0, 0, 0);
    }
    // C/D layout: row m = quad*4+r, col n = l16. Mask, sigmoid, reduce over cols.
    const int jA = j0 + ntA * 16 + l16;
    const int jB = j0 + ntB * 16 + l16;
    for (int r = 0; r < 4; ++r) {
        int m0 = i0 + quad * 4 + r;
        int m1 = m0 + 16;
        float v0 = ((jA <= m0) ? fsigm(c00[r] * inv_scale) : 0.f)
                 + ((jB <= m0) ? fsigm(c01[r] * inv_scale) : 0.f);
        float v1 = ((jA <= m1) ? fsigm(c10[r] * inv_scale) : 0.f)
                 + ((jB <= m1) ? fsigm(c11[r] * inv_scale) : 0.f);
        for (int o = 1; o < 16; o <<= 1) {
            v0 += __shfl_xor(v0, o, 64);
            v1 += __shfl_xor(v1, o, 64);
        }
        if (l16 == 0) {
            redg[(quad * 4 + r) * 4 + wave]      = v0;
            redg[(16 + quad * 4 + r) * 4 + wave] = v1;
        }
    }
    __syncthreads();
    if (t < 32) {
        float s2 = redg[t * 4] + redg[t * 4 + 1] + redg[t * 4 + 2] + redg[t * 4 + 3];
        g[t * 8] = s2;
    }
}

// ---------------- fused attn: scores + no-max softmax + PV (single pass) --------
// Byte-identical to the R11 kernel (best measured: 68.4 us).
__global__ __launch_bounds__(256) void cope_attn(
    const short* __restrict__ Q, const short* __restrict__ K,
    const short* __restrict__ Vt, const float* __restrict__ PE,
    const float* __restrict__ gts, short* __restrict__ AOb)
{
    const int it = (int)gridDim.x - 1 - (int)blockIdx.x;   // heavy tiles first
    const int h = blockIdx.y, b = blockIdx.z;
    const int i0 = it * 32;
    const int t = threadIdx.x, lane = t & 63, wave = t >> 6;
    const int quad = lane >> 4, l16 = lane & 15;

    __shared__ __align__(16) float Sld[32 * 132];   // setup: aliased as Q tile
    __shared__ __align__(16) short KV[128 * 72];    // PE / K[128][72] / V[64][136]
    __shared__ __align__(16) short Pb[32 * 136];
    __shared__ short qpeB[32 * 68];
    __shared__ float lrow[32];

    const float inv_scale = 0.125f;
    const int sr = t >> 3, ss = t & 7, irow = i0 + sr;

    float grow[8];
    {
        const float* gp = &gts[(((size_t)(b * Hh + h)) * Tt + i0 + sr) * 8];
        for (int k = 0; k < 8; ++k) grow[k] = gp[k];
    }
    float tot = 0.f;
    for (int k = 0; k < 8; ++k) tot += grow[k];

    short* QtS = (short*)Sld;
    {
        int r = t >> 3, c = t & 7;
        *(short8*)&QtS[r * 72 + c * 8] =
            *(const short8*)&Q[((size_t)(b * Tt + i0 + r)) * Dd + h * DHh + c * 8];
    }
    for (int e = 0; e < 16; ++e) {
        int idx = t + 256 * e;
        int p = idx >> 6, d = idx & 63;
        KV[p * 72 + d] = (short)f2bf(PE[((size_t)h * MAXPOS + p) * DHh + d]);
    }
    __syncthreads();

    short8 qa[2][2];
    for (int rb = 0; rb < 2; ++rb)
        for (int ks = 0; ks < 2; ++ks)
            qa[rb][ks] = *(short8*)&QtS[(rb * 16 + l16) * 72 + ks * 32 + quad * 8];

    // qpe table via MFMA (M=32, N=64, K=64)
    {
        int mt = wave >> 1;
        int ntA = 2 * (wave & 1), ntB = ntA + 1;
        floatx4 c0f = {0, 0, 0, 0}, c1f = {0, 0, 0, 0};
        for (int ks = 0; ks < 2; ++ks) {
            short8 b0 = *(short8*)&KV[(ntA * 16 + l16) * 72 + ks * 32 + quad * 8];
            short8 b1 = *(short8*)&KV[(ntB * 16 + l16) * 72 + ks * 32 + quad * 8];
            c0f = MFMA16(qa[mt][ks], b0, c0f, 0, 0, 0);
            c1f = MFMA16(qa[mt][ks], b1, c1f, 0, 0, 0);
        }
        for (int r = 0; r < 4; ++r) {
            qpeB[(mt * 16 + quad * 4 + r) * 68 + ntA * 16 + l16] = (short)f2bf(c0f[r]);
            qpeB[(mt * 16 + quad * 4 + r) * 68 + ntB * 16 + l16] = (short)f2bf(c1f[r]);
        }
    }

    const int JT = (i0 + 159) >> 7;
    floatx4 o0 = {0, 0, 0, 0}, o1 = {0, 0, 0, 0};
    const int pv_mt = wave >> 1;
    const int pv_ntA = 2 * (wave & 1), pv_ntB = pv_ntA + 1;
    float l_acc = 0.f;
    float baseAcc = 0.f;

    short8 kreg[4];
    for (int e = 0; e < 4; ++e) {
        int ch = t + 256 * e;
        int jr = ch >> 3, c = ch & 7;
        kreg[e] = *(const short8*)&K[((size_t)(b * Tt + jr)) * Dd + h * DHh + c * 8];
    }

    for (int jt = 0; jt < JT; ++jt) {
        const int j0 = jt * 128;
        __syncthreads();                                    // A: KV free
        for (int e = 0; e < 4; ++e) {
            int ch = t + 256 * e;
            int jr = ch >> 3, c = ch & 7;
            *(short8*)&KV[jr * 72 + c * 8] = kreg[e];
        }
        __syncthreads();                                    // B: K staged
        {
            int ntA = 2 * wave, ntB = ntA + 1;
            floatx4 c00 = {0,0,0,0}, c01 = {0,0,0,0}, c10 = {0,0,0,0}, c11 = {0,0,0,0};
            for (int ks = 0; ks < 2; ++ks) {
                short8 b0 = *(short8*)&KV[(ntA * 16 + l16) * 72 + ks * 32 + quad * 8];
                short8 b1 = *(short8*)&KV[(ntB * 16 + l16) * 72 + ks * 32 + quad * 8];
                c00 = MFMA16(qa[0][ks], b0, c00, 0, 0, 0);
                c01 = MFMA16(qa[0][ks], b1, c01, 0, 0, 0);
                c10 = MFMA16(qa[1][ks], b0, c10, 0, 0, 0);
                c11 = MFMA16(qa[1][ks], b1, c11, 0, 0, 0);
            }
            for (int r = 0; r < 4; ++r) {
                Sld[(quad * 4 + r) * 132 + ntA * 16 + l16] = c00[r];
                Sld[(quad * 4 + r) * 132 + ntB * 16 + l16] = c01[r];
                Sld[(16 + quad * 4 + r) * 132 + ntA * 16 + l16] = c10[r];
                Sld[(16 + quad * 4 + r) * 132 + ntB * 16 + l16] = c11[r];
            }
        }
        __syncthreads();                                    // C: S ready
        short8 vreg[4];
        for (int e = 0; e < 4; ++e) {
            int ch = t + 256 * e;
            int d = ch >> 4, c = ch & 15;
            vreg[e] = *(const short8*)&Vt[((size_t)(b * Dd + h * DHh + d)) * Tt + j0 + c * 8];
        }
        if (jt + 1 < JT) {
            for (int e = 0; e < 4; ++e) {
                int ch = t + 256 * e;
                int jr = ch >> 3, c = ch & 7;
                kreg[e] = *(const short8*)&K[((size_t)(b * Tt + j0 + 128 + jr)) * Dd + h * DHh + c * 8];
            }
        }
        {
            floatx4 qv[4];
            for (int q4 = 0; q4 < 4; ++q4)
                qv[q4] = *(floatx4*)&Sld[sr * 132 + ss * 16 + q4 * 4];
            float gt[16];
            float gs = 0.f;
            for (int e = 0; e < 16; ++e) {
                int j = j0 + ss * 16 + e;
                float qk = qv[e >> 2][e & 3];
                float g = (j <= irow) ? fsigm(qk * inv_scale) : 0.f;
                gt[e] = g;
                gs += g;
            }
            float inc = gs;
            for (int d2 = 1; d2 < 8; d2 <<= 1) {
                float n = __shfl_up(inc, d2, 64);
                if ((lane & 7) >= d2) inc += n;
            }
            float base = baseAcc + (inc - gs);
            float run = 0.f;
            short8 p0, p1;
            for (int e = 0; e < 16; ++e) {
                run += gt[e];
                int j = j0 + ss * 16 + e;
                float pos = tot - (base + run);
                pos = fminf(fmaxf(pos, 0.f), 63.f);
                float pf = floorf(pos);
                float al = pos - pf;
                int fi = (int)pf;
                int ci = fi + (al > 0.f ? 1 : 0);
                if (ci > 63) ci = 63;
                float qp = (1.f - al) * bf2fs(qpeB[sr * 68 + fi]) + al * bf2fs(qpeB[sr * 68 + ci]);
                float qk = qv[e >> 2][e & 3];
                float p = (j <= irow) ? __expf((qk + qp) * inv_scale) : 0.f;
                if (e < 8) p0[e] = (short)f2bf(p); else p1[e - 8] = (short)f2bf(p);
                l_acc += p;
            }
            *(short8*)&Pb[sr * 136 + ss * 16]     = p0;
            *(short8*)&Pb[sr * 136 + ss * 16 + 8] = p1;
            baseAcc += grow[jt];
        }
        for (int e = 0; e < 4; ++e) {
            int ch = t + 256 * e;
            int d = ch >> 4, c = ch & 15;
            *(short8*)&KV[d * 136 + c * 8] = vreg[e];
        }
        __syncthreads();                                    // D: Pb + V ready
        for (int ks = 0; ks < 4; ++ks) {
            short8 a  = *(short8*)&Pb[(pv_mt * 16 + l16) * 136 + ks * 32 + quad * 8];
            short8 b0 = *(short8*)&KV[(pv_ntA * 16 + l16) * 136 + ks * 32 + quad * 8];
            short8 b1 = *(short8*)&KV[(pv_ntB * 16 + l16) * 136 + ks * 32 + quad * 8];
            o0 = MFMA16(a, b0, o0, 0, 0, 0);
            o1 = MFMA16(a, b1, o1, 0, 0, 0);
        }
    }
    float lr = l_acc;
    for (int d2 = 4; d2 >= 1; d2 >>= 1) lr += __shfl_xor(lr, d2, 64);
    if (ss == 0) lrow[sr] = lr;
    __syncthreads();
    for (int r = 0; r < 4; ++r) {
        int row = pv_mt * 16 + quad * 4 + r;
        float inv = __builtin_amdgcn_rcpf(lrow[row]);
        size_t off = ((size_t)(b * Tt + i0 + row)) * Dd + h * DHh;
        AOb[off + pv_ntA * 16 + l16] = (short)f2bf(o0[r] * inv);
        AOb[off + pv_ntB * 16 + l16] = (short)f2bf(o1[r] * inv);
    }
}

// ---------------- launch ---------------------------------------------------------
extern "C" void kernel_launch(void* const* d_in, const int* in_sizes, int n_in,
                              void* d_out, int out_size, void* d_ws, size_t ws_size,
                              hipStream_t stream)
{
    const float* x  = (const float*)d_in[0];
    const float* Wq = (const float*)d_in[1];
    const float* bq = (const float*)d_in[2];
    const float* Wk = (const float*)d_in[3];
    const float* bk = (const float*)d_in[4];
    const float* Wv = (const float*)d_in[5];
    const float* bv = (const float*)d_in[6];
    const float* Wo = (const float*)d_in[7];
    const float* bo = (const float*)d_in[8];
    const float* pe = (const float*)d_in[9];
    // d_in[10]: causal mask (j > i) — structural, unused

    short* xb   = (short*)d_ws;                         //  4 MB
    short* Wqb  = xb   + (size_t)BTt * Dd;              //  2 MB
    short* Wkb  = Wqb  + (size_t)Dd * Dd;               //  2 MB
    short* Wvb  = Wkb  + (size_t)Dd * Dd;               //  2 MB
    short* Wob  = Wvb  + (size_t)Dd * Dd;               //  2 MB
    short* Qb   = Wob  + (size_t)Dd * Dd;               //  4 MB
    short* Kb   = Qb   + (size_t)BTt * Dd;              //  4 MB
    short* Vrow = Kb   + (size_t)BTt * Dd;              //  4 MB
    short* Vtg  = Vrow + (size_t)BTt * Dd;              //  4 MB
    short* AOb  = Vtg  + (size_t)BTt * Dd;              //  4 MB
    float* gts  = (float*)(AOb + (size_t)BTt * Dd);     //  1 MB

    dim3 gc(BTt * Dd / 8 / 256, 5);
    conv_bf16<<<gc, 256, 0, stream>>>(x, Wq, Wk, Wv, Wo, xb, Wqb, Wkb, Wvb, Wob);

    dim3 gq(BTt / BM, Dd / BN, 3);
    gemm_qkv<<<gq, 256, 0, stream>>>(xb, Wqb, Wkb, Wvb, bq, bk, bv, Qb, Kb, Vrow);

    dim3 gg(272, Hh, 2);    // x<256: gate sums; x>=256: V transpose (y = d-tile)
    vt_gates<<<gg, 256, 0, stream>>>(Qb, Kb, Vrow, Vtg, gts);

    dim3 ga(Tt / 32, Hh, 2);
    cope_attn<<<ga, 256, 0, stream>>>(Qb, Kb, Vtg, pe, gts, AOb);

    dim3 go(BTt / BM, Dd / BN, 1);
    gemm_o<<<go, 256, 0, stream>>>(AOb, Wob, bo, (float*)d_out);
}